// Round 8
// baseline (337.329 us; speedup 1.0000x reference)
//
#include <hip/hip_runtime.h>

#define NSAMP 32768
#define INF 512
#define OUTF 512
#define NB 8            // spline bases per input
#define KSP 4096        // INF * NB (spline columns)
#define KTOT 4608       // KSP + INF (silu columns)

typedef __attribute__((ext_vector_type(8))) short bf16x8;
typedef __attribute__((ext_vector_type(4))) float f32x4;

typedef __attribute__((address_space(1))) void gas_void;
typedef __attribute__((address_space(3))) void las_void;
#define GLL16(g, l) __builtin_amdgcn_global_load_lds( \
    (const gas_void*)(g), (las_void*)(l), 16, 0, 0)

// float -> bf16 round-nearest-even (W prep only)
__device__ __forceinline__ unsigned short f2bf(float f) {
  unsigned int u = __float_as_uint(f);
  u += 0x7fffu + ((u >> 16) & 1u);
  return (unsigned short)(u >> 16);
}

// pack two floats as bf16 pair (round-nearest-up). lo in low 16 bits.
__device__ __forceinline__ unsigned pack_rn(float lo, float hi) {
  return __builtin_amdgcn_perm(__float_as_uint(hi) + 0x8000u,
                               __float_as_uint(lo) + 0x8000u, 0x07060302u);
}

// 8-slot cubic B-spline basis vector, scaled by 6 (the 1/6 is folded into W).
// Branchless; out-of-grid x -> all-zero (matches reference clipping).
__device__ __forceinline__ uint4 kan_basis_vec(float xv) {
  float t = __builtin_fmaf(xv, 1.0f / 1.2f, 5.5f);   // (x+6.6)/1.2
  float cf = floorf(t);
  float u = t - cf;
  int j0 = (int)cf - 3;
  float omu = 1.0f - u;
  float u2 = u * u, u3 = u2 * u;
  float omu2 = omu * omu;
  float w0 = omu2 * omu;                                         // 6*(1/6)omu^3
  float w1 = __builtin_fmaf(3.f, u3, __builtin_fmaf(-6.f, u2, 4.f));
  float w2 = __builtin_fmaf(-3.f, u3,
              __builtin_fmaf(3.f, u2, __builtin_fmaf(3.f, u, 1.f)));
  float w3 = u3;
  unsigned P0 = pack_rn(w0, w1);
  unsigned P1 = pack_rn(w2, w3);
  // 128-bit result = [P1:P0] << (16*j0), bits outside [0,128) dropped.
  int p = j0 & 1;
  unsigned Q0 = p ? (P0 << 16) : P0;
  unsigned Q1 = p ? __builtin_amdgcn_alignbit(P1, P0, 16) : P1;
  unsigned Q2 = p ? (P1 >> 16) : 0u;
  int D = j0 >> 1;
  uint4 r;
  r.x = (D == 0) ? Q0 : (D == -1) ? Q1 : (D == -2) ? Q2 : 0u;
  r.y = (D == 1) ? Q0 : (D ==  0) ? Q1 : (D == -1) ? Q2 : 0u;
  r.z = (D == 2) ? Q0 : (D ==  1) ? Q1 : (D ==  0) ? Q2 : 0u;
  r.w = (D == 3) ? Q0 : (D ==  2) ? Q1 : (D ==  1) ? Q2 : 0u;
  return r;
}

// W_aug[o][KTOT]: cols i*8+k = spline_weight[o,i,k]*scaler[o,i]/6 (basis is 6w);
// col 4096+i = base_weight[o,i]
__global__ __launch_bounds__(256) void kan_prep_w(
    const float* __restrict__ bw, const float* __restrict__ sw,
    const float* __restrict__ sc, unsigned short* __restrict__ W) {
  int idx = blockIdx.x * 256 + threadIdx.x;   // o*512 + i
  float scv = sc[idx] * (1.0f / 6.0f);
  float4 s0 = ((const float4*)sw)[idx * 2 + 0];
  float4 s1 = ((const float4*)sw)[idx * 2 + 1];
  unsigned short v[8];
  v[0] = f2bf(s0.x * scv); v[1] = f2bf(s0.y * scv);
  v[2] = f2bf(s0.z * scv); v[3] = f2bf(s0.w * scv);
  v[4] = f2bf(s1.x * scv); v[5] = f2bf(s1.y * scv);
  v[6] = f2bf(s1.z * scv); v[7] = f2bf(s1.w * scv);
  int o = idx >> 9, i = idx & 511;
  *(bf16x8*)(W + (size_t)o * KTOT + i * NB) = *(bf16x8*)v;
  W[(size_t)o * KTOT + KSP + i] = f2bf(bw[idx]);
}

// One 16-MFMA cluster: mf rows mbase..mbase+3 x 4 nf cols.
__device__ __forceinline__ void mfma16(
    f32x4 acc[8][4], int mbase, const bf16x8 av[4], const bf16x8 bv[4]) {
  #pragma unroll
  for (int mf = 0; mf < 4; ++mf)
    #pragma unroll
    for (int g = 0; g < 4; ++g)
      acc[mbase + mf][g] = __builtin_amdgcn_mfma_f32_16x16x32_bf16(
          av[mf], bv[g], acc[mbase + mf][g], 0, 0, 0);
}

// Fused out = A_aug(x) @ W_aug^T -- m201 8-wave 256x256 geometry.
// Block: 512 thr / 8 waves (2M x 4N), per-wave 128x64 output, acc 128 AGPR.
// Both As (eval-produced) and Bs (GLL-staged) double-buffered; K-step = 64.
// Per step, 4 phases, each {phase loads/evals -> sched_pin -> s_barrier ->
// lgkmcnt(0) -> sched_pin -> setprio(1) 16xMFMA setprio(0) -> s_barrier}:
//  P0: x-prefetch(k+1) [oldest]; GLL B(k+1) x2; read avA/bvA (ks0); C0=mf0-3.
//  P1: GLL x1; eval slice 1 -> An; read avB (ks0);            C1=mf4-7,ks0.
//  P2: GLL x1; [silu x2 prefetch]; read avA/bvB (ks1);        C2=mf0-3,ks1.
//  P3: eval slice 2 -> An; read avB(ks1); vmcnt(0)+lgkm(0);   C3=mf4-7,ks1.
// Hazards are cross-step only (both LDS operands dbuf'd): P3's pre-barrier
// full drain (GLLs issued >=1 phase earlier; writes from P1/P3) + its two
// barriers precede the k+1 P0 reads. x-prefetches issue BEFORE the GLLs so
// their auto-waits retire only themselves (oldest-first).
__global__ __launch_bounds__(512, 2) void kan_fused(
    const float* __restrict__ x, const unsigned short* __restrict__ W,
    float* __restrict__ out) {
  __shared__ __align__(16) unsigned short As[2][256 * 64];   // 64 KB dbuf
  __shared__ __align__(16) unsigned short Bs[2][256 * 64];   // 64 KB dbuf
  const int tid = threadIdx.x;
  const int wave = tid >> 6;
  const int lane = tid & 63;
  const int frow = lane & 15;
  const int quad = lane >> 4;
  const int lr = lane >> 3;     // row within 8-row staging group
  const int lc = lane & 7;      // 16B-seg within staging group
  const int mtile = blockIdx.x & 127;
  const int ntile = blockIdx.x >> 7;          // 0..1 (siblings 128 apart: same XCD)
  const int wm = (wave & 1) << 7;             // 0 / 128
  const int wn = (wave >> 1) << 6;            // 0 / 64 / 128 / 192
  const int fr7 = frow & 7;
  const int sa0 = (quad ^ fr7) * 8;           // ks=0 swizzled seg offset
  const int sa1 = ((4 + quad) ^ fr7) * 8;     // ks=1

  f32x4 acc[8][4];
  #pragma unroll
  for (int i = 0; i < 8; ++i)
    #pragma unroll
    for (int j = 0; j < 4; ++j)
      acc[i][j] = (f32x4){0.f, 0.f, 0.f, 0.f};

  // B staging: 4 GLL rounds/step; round ir covers rows ir*64 + wave*8 + lr,
  // seg source-XORed by lr so the lane-linear deposit lands swizzled.
  const unsigned short* bg = W +
      (size_t)(ntile * 256 + wave * 8 + lr) * KTOT + ((lc ^ lr) * 8);
  const float* xb = x + (size_t)mtile * 256 * INF;
  // A-eval assignment: thread -> row rt, seg-half `half` (4 segs each).
  const int rt = tid >> 1;
  const int half = tid & 1;
  const int rt7 = rt & 7;
  const float* xs_sp = xb + (size_t)rt * INF + half * 4;    // spline x src
  const float* xs_si = xb + (size_t)rt * INF + half * 32;   // silu x src

  // ---- Prologue: A(0) evals -> As[0]; GLL B(0) -> Bs[0] ----
  {
    float4 xv = *(const float4*)xs_sp;    // inputs half*4 .. +3 of chunk 0
    #pragma unroll
    for (int ir = 0; ir < 4; ++ir)
      GLL16(bg + (size_t)ir * (64 * KTOT), &Bs[0][(ir * 64 + wave * 8) * 64]);
    bg += 64;
    float xe[4] = {xv.x, xv.y, xv.z, xv.w};
    #pragma unroll
    for (int e = 0; e < 4; ++e) {
      uint4 bb = kan_basis_vec(xe[e]);
      *(uint4*)&As[0][rt * 64 + (((half * 4 + e) ^ rt7) * 8)] = bb;
    }
    __syncthreads();   // drains GLL + xv + ds_writes, publishes both
  }

  // ---- Main loop: 72 steps (64 spline + 8 silu) ----
  for (int k = 0; k < 72; ++k) {
    const unsigned short* Ac = As[k & 1];
    const unsigned short* Bc = Bs[k & 1];
    unsigned short* An = As[(k + 1) & 1];
    unsigned short* Bn = Bs[(k + 1) & 1];
    const bool spl = (k < 63);
    const bool sil = (k >= 63) && (k < 71);
    const int scn = k - 63;                 // silu chunk being prepared

    bf16x8 avA[4], avB[4], bvA[4], bvB[4];
    float4 xv;
    float4 xq0[4];

    // ================= P0 =================
    if (spl) {
      xv = *(const float4*)(xs_sp + (size_t)(k + 1) * 8);
    } else if (sil) {
      const float* xr = xs_si + scn * 64;
      xq0[0] = *(const float4*)(xr + 0);
      xq0[1] = *(const float4*)(xr + 4);
      xq0[2] = *(const float4*)(xr + 8);
      xq0[3] = *(const float4*)(xr + 12);
    }
    if (k < 71) {
      GLL16(bg, &Bn[(wave * 8) * 64]);
      GLL16(bg + (size_t)(64 * KTOT), &Bn[(64 + wave * 8) * 64]);
    }
    #pragma unroll
    for (int f = 0; f < 4; ++f)
      avA[f] = *(const bf16x8*)&Ac[(wm + f * 16 + frow) * 64 + sa0];
    #pragma unroll
    for (int g = 0; g < 4; ++g)
      bvA[g] = *(const bf16x8*)&Bc[(wn + g * 16 + frow) * 64 + sa0];
    __builtin_amdgcn_sched_barrier(0);
    __builtin_amdgcn_s_barrier();
    asm volatile("s_waitcnt lgkmcnt(0)");
    __builtin_amdgcn_sched_barrier(0);
    __builtin_amdgcn_s_setprio(1);
    mfma16(acc, 0, avA, bvA);
    __builtin_amdgcn_s_setprio(0);
    __builtin_amdgcn_s_barrier();

    // ================= P1 =================
    if (k < 71)
      GLL16(bg + (size_t)(128 * KTOT), &Bn[(128 + wave * 8) * 64]);
    if (spl) {
      uint4 b0 = kan_basis_vec(xv.x);
      uint4 b1 = kan_basis_vec(xv.y);
      *(uint4*)&An[rt * 64 + (((half * 4 + 0) ^ rt7) * 8)] = b0;
      *(uint4*)&An[rt * 64 + (((half * 4 + 1) ^ rt7) * 8)] = b1;
    } else if (sil) {
      float a[16] = {xq0[0].x, xq0[0].y, xq0[0].z, xq0[0].w,
                     xq0[1].x, xq0[1].y, xq0[1].z, xq0[1].w,
                     xq0[2].x, xq0[2].y, xq0[2].z, xq0[2].w,
                     xq0[3].x, xq0[3].y, xq0[3].z, xq0[3].w};
      float sl[16];
      #pragma unroll
      for (int e = 0; e < 16; ++e)
        sl[e] = a[e] * __builtin_amdgcn_rcpf(1.0f + __expf(-a[e]));
      uint4 p0, p1;
      p0.x = pack_rn(sl[0], sl[1]);   p0.y = pack_rn(sl[2], sl[3]);
      p0.z = pack_rn(sl[4], sl[5]);   p0.w = pack_rn(sl[6], sl[7]);
      p1.x = pack_rn(sl[8], sl[9]);   p1.y = pack_rn(sl[10], sl[11]);
      p1.z = pack_rn(sl[12], sl[13]); p1.w = pack_rn(sl[14], sl[15]);
      *(uint4*)&An[rt * 64 + (((half * 4 + 0) ^ rt7) * 8)] = p0;
      *(uint4*)&An[rt * 64 + (((half * 4 + 1) ^ rt7) * 8)] = p1;
    }
    #pragma unroll
    for (int f = 0; f < 4; ++f)
      avB[f] = *(const bf16x8*)&Ac[(wm + (f + 4) * 16 + frow) * 64 + sa0];
    __builtin_amdgcn_sched_barrier(0);
    __builtin_amdgcn_s_barrier();
    asm volatile("s_waitcnt lgkmcnt(0)");
    __builtin_amdgcn_sched_barrier(0);
    __builtin_amdgcn_s_setprio(1);
    mfma16(acc, 4, avB, bvA);
    __builtin_amdgcn_s_setprio(0);
    __builtin_amdgcn_s_barrier();

    // ================= P2 =================
    float4 xq1[4];
    if (k < 71)
      GLL16(bg + (size_t)(192 * KTOT), &Bn[(192 + wave * 8) * 64]);
    if (sil) {
      const float* xr = xs_si + scn * 64 + 16;
      xq1[0] = *(const float4*)(xr + 0);
      xq1[1] = *(const float4*)(xr + 4);
      xq1[2] = *(const float4*)(xr + 8);
      xq1[3] = *(const float4*)(xr + 12);
    }
    #pragma unroll
    for (int f = 0; f < 4; ++f)
      avA[f] = *(const bf16x8*)&Ac[(wm + f * 16 + frow) * 64 + sa1];
    #pragma unroll
    for (int g = 0; g < 4; ++g)
      bvB[g] = *(const bf16x8*)&Bc[(wn + g * 16 + frow) * 64 + sa1];
    __builtin_amdgcn_sched_barrier(0);
    __builtin_amdgcn_s_barrier();
    asm volatile("s_waitcnt lgkmcnt(0)");
    __builtin_amdgcn_sched_barrier(0);
    __builtin_amdgcn_s_setprio(1);
    mfma16(acc, 0, avA, bvB);
    __builtin_amdgcn_s_setprio(0);
    __builtin_amdgcn_s_barrier();

    // ================= P3 =================
    if (spl) {
      uint4 b2 = kan_basis_vec(xv.z);
      uint4 b3 = kan_basis_vec(xv.w);
      *(uint4*)&An[rt * 64 + (((half * 4 + 2) ^ rt7) * 8)] = b2;
      *(uint4*)&An[rt * 64 + (((half * 4 + 3) ^ rt7) * 8)] = b3;
    } else if (sil) {
      float a[16] = {xq1[0].x, xq1[0].y, xq1[0].z, xq1[0].w,
                     xq1[1].x, xq1[1].y, xq1[1].z, xq1[1].w,
                     xq1[2].x, xq1[2].y, xq1[2].z, xq1[2].w,
                     xq1[3].x, xq1[3].y, xq1[3].z, xq1[3].w};
      float sl[16];
      #pragma unroll
      for (int e = 0; e < 16; ++e)
        sl[e] = a[e] * __builtin_amdgcn_rcpf(1.0f + __expf(-a[e]));
      uint4 p2, p3;
      p2.x = pack_rn(sl[0], sl[1]);   p2.y = pack_rn(sl[2], sl[3]);
      p2.z = pack_rn(sl[4], sl[5]);   p2.w = pack_rn(sl[6], sl[7]);
      p3.x = pack_rn(sl[8], sl[9]);   p3.y = pack_rn(sl[10], sl[11]);
      p3.z = pack_rn(sl[12], sl[13]); p3.w = pack_rn(sl[14], sl[15]);
      *(uint4*)&An[rt * 64 + (((half * 4 + 2) ^ rt7) * 8)] = p2;
      *(uint4*)&An[rt * 64 + (((half * 4 + 3) ^ rt7) * 8)] = p3;
    }
    #pragma unroll
    for (int f = 0; f < 4; ++f)
      avB[f] = *(const bf16x8*)&Ac[(wm + (f + 4) * 16 + frow) * 64 + sa1];
    // full drain: GLL(k+1) (issued 1-3 phases ago), eval-writes, own reads.
    asm volatile("s_waitcnt vmcnt(0) lgkmcnt(0)");
    __builtin_amdgcn_sched_barrier(0);
    __builtin_amdgcn_s_barrier();
    __builtin_amdgcn_sched_barrier(0);
    __builtin_amdgcn_s_setprio(1);
    mfma16(acc, 4, avB, bvB);
    __builtin_amdgcn_s_setprio(0);
    __builtin_amdgcn_s_barrier();

    bg += 64;
  }

  // ---- Epilogue ----
  const size_t m0 = (size_t)mtile * 256;
  const int n0 = ntile * 256;
  #pragma unroll
  for (int mf = 0; mf < 8; ++mf)
    #pragma unroll
    for (int nf = 0; nf < 4; ++nf)
      #pragma unroll
      for (int r = 0; r < 4; ++r)
        out[(m0 + wm + mf * 16 + quad * 4 + r) * OUTF +
            (n0 + wn + nf * 16 + frow)] = acc[mf][nf][r];
}

// Correct-but-slow fp32 fallback (only if ws can't hold W_aug: 4.7 MB)
__global__ __launch_bounds__(256) void kan_naive(
    const float* __restrict__ x, const float* __restrict__ bw,
    const float* __restrict__ sw, const float* __restrict__ sc,
    float* __restrict__ out) {
  int idx = blockIdx.x * 256 + threadIdx.x;
  int n = idx >> 9, o = idx & 511;
  const float* xr = x + (size_t)n * INF;
  float acc = 0.f;
  for (int i = 0; i < INF; ++i) {
    float xv = xr[i];
    float sil = xv / (1.0f + __expf(-xv));
    float t = (xv + 6.6f) * (1.0f / 1.2f);
    float cf = floorf(t);
    float u = t - cf;
    int j0 = (int)cf - 3;
    float omu = 1.0f - u;
    float u2 = u * u, u3 = u2 * u;
    float w[4];
    w[0] = (1.0f / 6.0f) * omu * omu * omu;
    w[1] = (1.0f / 6.0f) * (3.0f * u3 - 6.0f * u2 + 4.0f);
    w[2] = (1.0f / 6.0f) * (-3.0f * u3 + 3.0f * u2 + 3.0f * u + 1.0f);
    w[3] = (1.0f / 6.0f) * u3;
    int wi = o * INF + i;
    acc += sil * bw[wi];
    float sp = 0.f;
    #pragma unroll
    for (int m = 0; m < 4; ++m) {
      int j = j0 + m;
      if ((unsigned)j < 8u) sp += w[m] * sw[wi * NB + j];
    }
    acc += sp * sc[wi];
  }
  out[idx] = acc;
}

extern "C" void kernel_launch(void* const* d_in, const int* in_sizes, int n_in,
                              void* d_out, int out_size, void* d_ws, size_t ws_size,
                              hipStream_t stream) {
  const float* x  = (const float*)d_in[0];
  const float* bw = (const float*)d_in[1];
  const float* sw = (const float*)d_in[2];
  const float* sc = (const float*)d_in[3];
  float* out = (float*)d_out;

  const size_t wbytes = (size_t)OUTF * KTOT * 2;    // 4.72 MB
  if (ws_size >= wbytes) {
    unsigned short* W = (unsigned short*)d_ws;
    kan_prep_w<<<(OUTF * INF) / 256, 256, 0, stream>>>(bw, sw, sc, W);
    kan_fused<<<(NSAMP / 256) * (OUTF / 256), 512, 0, stream>>>(x, W, out);
  } else {
    kan_naive<<<(NSAMP * OUTF) / 256, 256, 0, stream>>>(x, bw, sw, sc, out);
  }
}